// Round 1
// baseline (1200.019 us; speedup 1.0000x reference)
//
#include <hip/hip_runtime.h>
#include <math.h>

// ---- problem constants ----
#define B   64
#define L   64
#define C   16
#define CHD 64
#define EMB 300
#define D   450       // EMB + 3*50
#define NT  (B*L)     // 4096 tokens per branch

// ---------------- wave helpers (wave64) ----------------
__device__ inline float wave_sum(float v) {
#pragma unroll
    for (int o = 32; o; o >>= 1) v += __shfl_xor(v, o, 64);
    return v;
}
__device__ inline float wave_max(float v) {
#pragma unroll
    for (int o = 32; o; o >>= 1) v = fmaxf(v, __shfl_xor(v, o, 64));
    return v;
}

// ---------------- kernel 1: word emb + char conv features ----------------
template <int K>
__device__ inline float conv_filter(const float e[C][CHD], const float* __restrict__ wp,
                                    float bias) {
    const int P = C - K + 1;
    float acc[P];
#pragma unroll
    for (int p = 0; p < P; ++p) acc[p] = 0.f;
    for (int d = 0; d < CHD; ++d) {
#pragma unroll
        for (int k = 0; k < K; ++k) {
            float wv = wp[d * K + k];
#pragma unroll
            for (int p = 0; p < P; ++p) acc[p] += e[p + k][d] * wv;
        }
    }
    float m = acc[0];
#pragma unroll
    for (int p = 1; p < P; ++p) m = fmaxf(m, acc[p]);
    return fmaxf(0.f, m + bias);
}

__global__ __launch_bounds__(192) void embed_conv_kernel(
    const int* __restrict__ q1, const int* __restrict__ q2,
    const int* __restrict__ q1c, const int* __restrict__ q2c,
    const float* __restrict__ word_emb, const float* __restrict__ char_emb,
    const float* __restrict__ w3, const float* __restrict__ b3,
    const float* __restrict__ w4, const float* __restrict__ b4,
    const float* __restrict__ w5, const float* __restrict__ b5,
    float* __restrict__ xout)
{
    const int bid    = blockIdx.x;        // 0 .. 2*NT-1
    const int branch = bid >> 12;         // / 4096
    const int tok    = bid & (NT - 1);
    const int tid    = threadIdx.x;

    const int* q  = branch ? q2  : q1;
    const int* qc = branch ? q2c : q1c;

    __shared__ int   ch[C];
    __shared__ float e[C][CHD];           // 4 KB

    if (tid < C) ch[tid] = qc[tok * C + tid];
    __syncthreads();
    for (int idx = tid; idx < C * CHD; idx += 192) {
        int p = idx >> 6, d = idx & 63;
        e[p][d] = char_emb[(size_t)ch[p] * CHD + d];
    }

    // word embedding copy (independent of LDS)
    const int w = q[tok];
    float* xbase = xout + (size_t)bid * D;
    for (int d = tid; d < EMB; d += 192)
        xbase[d] = word_emb[(size_t)w * EMB + d];
    __syncthreads();

    if (tid < 150) {
        const int f = tid;
        float r;
        if (f < 50)        r = conv_filter<3>(e, w3 + (size_t)f * CHD * 3,        b3[f]);
        else if (f < 100)  r = conv_filter<4>(e, w4 + (size_t)(f - 50) * CHD * 4, b4[f - 50]);
        else               r = conv_filter<5>(e, w5 + (size_t)(f - 100) * CHD * 5, b5[f - 100]);
        xbase[EMB + f] = r;
    }
}

// ---------------- kernel 2: highway layer (fused GEMM + gate) ----------------
// y = x @ W^T + b ; g = sigmoid(y) ; out = g*relu(y) + (1-g)*x
#define BM 64
#define BN 64
#define BK 16

__global__ __launch_bounds__(256) void highway_kernel(
    const float* __restrict__ x, const float* __restrict__ W,
    const float* __restrict__ bvec, float* __restrict__ out)
{
    const int tid = threadIdx.x;
    const int tx = tid & 15, ty = tid >> 4;
    const int n0 = blockIdx.x * BN;   // cols (0..449, tiles of 64 -> 8)
    const int m0 = blockIdx.y * BM;   // rows (8192 -> 128)

    __shared__ float As[BK][BM + 1];
    __shared__ float Bs[BK][BN + 1];

    float acc[4][4] = {};
    for (int k0 = 0; k0 < D; k0 += BK) {
        for (int idx = tid; idx < BM * BK; idx += 256) {
            int m = idx >> 4, k = idx & 15;
            int gk = k0 + k;
            As[k][m] = (gk < D) ? x[(size_t)(m0 + m) * D + gk] : 0.f;
        }
        for (int idx = tid; idx < BN * BK; idx += 256) {
            int n = idx >> 4, k = idx & 15;
            int gk = k0 + k, gn = n0 + n;
            Bs[k][n] = (gn < D && gk < D) ? W[(size_t)gn * D + gk] : 0.f;
        }
        __syncthreads();
#pragma unroll
        for (int kk = 0; kk < BK; ++kk) {
            float a[4], b[4];
#pragma unroll
            for (int i = 0; i < 4; ++i) a[i] = As[kk][ty * 4 + i];
#pragma unroll
            for (int j = 0; j < 4; ++j) b[j] = Bs[kk][tx * 4 + j];
#pragma unroll
            for (int i = 0; i < 4; ++i)
#pragma unroll
                for (int j = 0; j < 4; ++j) acc[i][j] += a[i] * b[j];
        }
        __syncthreads();
    }
#pragma unroll
    for (int i = 0; i < 4; ++i) {
        const int m = m0 + ty * 4 + i;
#pragma unroll
        for (int j = 0; j < 4; ++j) {
            const int n = n0 + tx * 4 + j;
            if (n < D) {
                float y  = acc[i][j] + bvec[n];
                float g  = 1.f / (1.f + expf(-y));
                float xo = x[(size_t)m * D + n];
                out[(size_t)m * D + n] = g * fmaxf(y, 0.f) + (1.f - g) * xo;
            }
        }
    }
}

// ---------------- kernel 3: additive self-attention ----------------
// one wave per (branch, b, i)
__global__ __launch_bounds__(64) void attn_kernel(
    const float* __restrict__ x,
    const int* __restrict__ q1_len, const int* __restrict__ q2_len,
    const float* __restrict__ attn_w, const float* __restrict__ attn_b,
    int layer, float* __restrict__ att_out)
{
    const int bid    = blockIdx.x;           // 0..8191
    const int branch = bid >> 12;
    const int rem    = bid & (NT - 1);
    const int b      = rem >> 6;
    const int i      = rem & 63;
    const int j      = threadIdx.x;          // 0..63 (one wave)

    const float* w1 = attn_w + (size_t)layer * 3 * D;
    const float* w2 = w1 + D;
    const float* w3 = w2 + D;
    const float bias = attn_b[layer];
    const int   len  = (branch ? q2_len : q1_len)[b];

    const float* xb = x + ((size_t)(branch * B + b)) * L * D;
    const float* xi = xb + (size_t)i * D;

    __shared__ float xis[D];
    float p1 = 0.f;
    for (int d = j; d < D; d += 64) {
        float v = xi[d];
        xis[d] = v;
        p1 += v * w1[d];
    }
    __syncthreads();
    const float s1 = wave_sum(p1);

    const float* xj = xb + (size_t)j * D;
    float s2 = 0.f, dot = 0.f;
    for (int d = 0; d < D; ++d) {
        float xv = xj[d];
        s2  += xv * w2[d];
        dot += xv * w3[d] * xis[d];
    }
    float score = s1 + s2 + dot + bias;
    if (j >= len) score = -1e-9f;            // reference's (buggy) mask value

    const float m    = wave_max(score);
    const float ev   = expf(score - m);
    const float ssum = wave_sum(ev);
    const float a    = ev / ssum;

    __shared__ float as[L];
    as[j] = a;
    __syncthreads();

    float* ao = att_out + ((size_t)(branch * B + b)) * L * D + (size_t)i * D;
    for (int d = j; d < D; d += 64) {
        float accv = 0.f;
#pragma unroll 8
        for (int jj = 0; jj < L; ++jj)
            accv += as[jj] * xb[(size_t)jj * D + d];
        ao[d] = accv;
    }
}

// ---------------- kernel 4: x += att ----------------
__global__ __launch_bounds__(256) void add_kernel(
    float* __restrict__ x, const float* __restrict__ a, int n)
{
    int i = blockIdx.x * 256 + threadIdx.x;
    if (i < n) x[i] += a[i];
}

// ---------------- launch ----------------
extern "C" void kernel_launch(void* const* d_in, const int* in_sizes, int n_in,
                              void* d_out, int out_size, void* d_ws, size_t ws_size,
                              hipStream_t stream) {
    const int*   q1       = (const int*)  d_in[0];
    const int*   q2       = (const int*)  d_in[1];
    const int*   q1_len   = (const int*)  d_in[2];
    const int*   q2_len   = (const int*)  d_in[3];
    const int*   q1c      = (const int*)  d_in[4];
    const int*   q2c      = (const int*)  d_in[5];
    const float* word_emb = (const float*)d_in[6];
    const float* char_emb = (const float*)d_in[7];
    const float* w3       = (const float*)d_in[8];
    const float* b3       = (const float*)d_in[9];
    const float* w4       = (const float*)d_in[10];
    const float* b4       = (const float*)d_in[11];
    const float* w5       = (const float*)d_in[12];
    const float* b5       = (const float*)d_in[13];
    const float* hw_w     = (const float*)d_in[14];
    const float* hw_b     = (const float*)d_in[15];
    const float* attn_w   = (const float*)d_in[16];
    const float* attn_b   = (const float*)d_in[17];
    float* out = (float*)d_out;

    float* buf0 = (float*)d_ws;
    float* buf1 = buf0 + (size_t)2 * NT * D;

    // 1. embed + char conv -> buf0  (both branches)
    embed_conv_kernel<<<2 * NT, 192, 0, stream>>>(
        q1, q2, q1c, q2c, word_emb, char_emb, w3, b3, w4, b4, w5, b5, buf0);

    // 2. highway x2 (ping-pong)
    dim3 hgrid((D + BN - 1) / BN, (2 * NT) / BM);
    highway_kernel<<<hgrid, 256, 0, stream>>>(buf0, hw_w, hw_b, buf1);
    highway_kernel<<<hgrid, 256, 0, stream>>>(buf1, hw_w, hw_b, buf0);

    // 3. attn layer 0 -> buf1 ; x += att
    attn_kernel<<<2 * NT, 64, 0, stream>>>(buf0, q1_len, q2_len, attn_w, attn_b, 0, buf1);
    add_kernel<<<(2 * NT * D + 255) / 256, 256, 0, stream>>>(buf0, buf1, 2 * NT * D);

    // 4. attn layer 1 -> d_out (returned value is the last att, not x)
    attn_kernel<<<2 * NT, 64, 0, stream>>>(buf0, q1_len, q2_len, attn_w, attn_b, 1, out);
}

// Round 2
// 938.162 us; speedup vs baseline: 1.2791x; 1.2791x over previous
//
#include <hip/hip_runtime.h>
#include <math.h>

// ---- problem constants ----
#define B   64
#define L   64
#define C   16
#define CHD 64
#define EMB 300
#define D   450       // EMB + 3*50
#define NT  (B*L)     // 4096 tokens per branch

// ---------------- wave helpers (wave64) ----------------
__device__ inline float wave_sum(float v) {
#pragma unroll
    for (int o = 32; o; o >>= 1) v += __shfl_xor(v, o, 64);
    return v;
}
__device__ inline float wave_max(float v) {
#pragma unroll
    for (int o = 32; o; o >>= 1) v = fmaxf(v, __shfl_xor(v, o, 64));
    return v;
}

// ---------------- kernel 0: word embedding copy ----------------
// 4 tokens per block of 256
__global__ __launch_bounds__(256) void wordcopy_kernel(
    const int* __restrict__ q1, const int* __restrict__ q2,
    const float* __restrict__ word_emb, float* __restrict__ xout)
{
    const int tid = threadIdx.x;
#pragma unroll
    for (int t = 0; t < 4; ++t) {
        const int tok    = blockIdx.x * 4 + t;
        const int branch = tok >> 12;
        const int tokl   = tok & (NT - 1);
        const int w      = (branch ? q2 : q1)[tokl];
        const float* src = word_emb + (size_t)w * EMB;
        float*       dst = xout + (size_t)tok * D;
        for (int d = tid; d < EMB; d += 256) dst[d] = src[d];
    }
}

// ---------------- kernel 1: char conv (per-K-group), LDS weights ----------------
// block = 256 (4 waves); each wave processes 8 tokens; lane = filter (f<50 active)
// weights in LDS, float2-packed over d-halves: wl2[(d2*K+k)*50+f] = {w[f][d2][k], w[f][d2+32][k]}
template <int K, int OFF>
__global__ __launch_bounds__(256) void conv_kernel(
    const int* __restrict__ q1c, const int* __restrict__ q2c,
    const float* __restrict__ char_emb,
    const float* __restrict__ wconv, const float* __restrict__ bias,
    float* __restrict__ xout)
{
    const int P = C - K + 1;
    const int tid  = threadIdx.x;
    const int w    = tid >> 6;         // wave 0..3
    const int lane = tid & 63;
    const int f    = (lane < 50) ? lane : 49;   // clamp to keep LDS reads in-bounds

    __shared__ float2 wl2[32 * K * 50];         // K=5: 62.5 KB
    __shared__ float  es[4][16 * 64];           // 16 KB, per-wave e tile (d-interleaved)

    // one-time weight staging (coalesced global reads)
    const int N2 = 32 * K * 50;
    for (int idx = tid; idx < N2; idx += 256) {
        int fr   = idx % 50;
        int rest = idx / 50;
        int k    = rest % K;
        int d2   = rest / K;
        const float* wp = wconv + (size_t)fr * CHD * K;
        wl2[idx] = make_float2(wp[d2 * K + k], wp[(d2 + 32) * K + k]);
    }
    const float bf = (lane < 50) ? bias[f] : 0.f;

#pragma unroll 1
    for (int t = 0; t < 8; ++t) {
        __syncthreads();   // weights ready (iter 0) + WAR on es (later iters)
        const int tok    = blockIdx.x * 32 + w * 8 + t;
        const int branch = tok >> 12;
        const int tokl   = tok & (NT - 1);
        const int* qcrow = (branch ? q2c : q1c) + (size_t)tokl * C;

        int chv = (lane < 16) ? qcrow[lane] : 0;
        const int d2w = lane & 31, hw_ = lane >> 5;
#pragma unroll
        for (int r = 0; r < C; ++r) {
            int c = __shfl(chv, r, 64);
            es[w][r * 64 + d2w * 2 + hw_] = char_emb[(size_t)c * CHD + lane];
        }
        __syncthreads();

        const float2* es2 = (const float2*)es[w];
        float2 acc2[P];
#pragma unroll
        for (int p = 0; p < P; ++p) acc2[p] = make_float2(0.f, 0.f);

#pragma unroll 1
        for (int d2 = 0; d2 < 32; ++d2) {
            float2 e2[C];
#pragma unroll
            for (int r = 0; r < C; ++r) e2[r] = es2[r * 32 + d2];
#pragma unroll
            for (int k = 0; k < K; ++k) {
                float2 wv = wl2[(d2 * K + k) * 50 + f];
#pragma unroll
                for (int p = 0; p < P; ++p) {
                    acc2[p].x = fmaf(e2[p + k].x, wv.x, acc2[p].x);
                    acc2[p].y = fmaf(e2[p + k].y, wv.y, acc2[p].y);
                }
            }
        }
        float m = acc2[0].x + acc2[0].y;
#pragma unroll
        for (int p = 1; p < P; ++p) m = fmaxf(m, acc2[p].x + acc2[p].y);
        float r = fmaxf(0.f, m + bf);
        if (lane < 50)
            xout[(size_t)tok * D + EMB + OFF + lane] = r;
    }
}

// ---------------- kernel 2: highway layer (fused GEMM + gate) ----------------
// 128x64 tile, 8x4 microtile, BK=16
#define BM 128
#define BN 64
#define BK 16

__global__ __launch_bounds__(256) void highway_kernel(
    const float* __restrict__ x, const float* __restrict__ W,
    const float* __restrict__ bvec, float* __restrict__ out)
{
    const int tid = threadIdx.x;
    const int tx = tid & 15, ty = tid >> 4;     // ty 0..15
    const int n0 = blockIdx.x * BN;
    const int m0 = blockIdx.y * BM;

    __shared__ float As[BK][BM + 4];
    __shared__ float Bs[BK][BN + 4];

    float acc[8][4] = {};
    for (int k0 = 0; k0 < D; k0 += BK) {
        for (int idx = tid; idx < BM * BK; idx += 256) {
            int m = idx >> 4, k = idx & 15;
            int gk = k0 + k;
            As[k][m] = (gk < D) ? x[(size_t)(m0 + m) * D + gk] : 0.f;
        }
        for (int idx = tid; idx < BN * BK; idx += 256) {
            int n = idx >> 4, k = idx & 15;
            int gk = k0 + k, gn = n0 + n;
            Bs[k][n] = (gn < D && gk < D) ? W[(size_t)gn * D + gk] : 0.f;
        }
        __syncthreads();
#pragma unroll
        for (int kk = 0; kk < BK; ++kk) {
            float4 a0 = *(const float4*)&As[kk][ty * 4];
            float4 a1 = *(const float4*)&As[kk][64 + ty * 4];
            float4 b  = *(const float4*)&Bs[kk][tx * 4];
            const float av[8] = {a0.x, a0.y, a0.z, a0.w, a1.x, a1.y, a1.z, a1.w};
            const float bv[4] = {b.x, b.y, b.z, b.w};
#pragma unroll
            for (int i = 0; i < 8; ++i)
#pragma unroll
                for (int j = 0; j < 4; ++j) acc[i][j] = fmaf(av[i], bv[j], acc[i][j]);
        }
        __syncthreads();
    }
#pragma unroll
    for (int i = 0; i < 8; ++i) {
        const int m = m0 + ((i < 4) ? (ty * 4 + i) : (64 + ty * 4 + i - 4));
#pragma unroll
        for (int j = 0; j < 4; ++j) {
            const int n = n0 + tx * 4 + j;
            if (n < D) {
                float y  = acc[i][j] + bvec[n];
                float g  = 1.f / (1.f + __expf(-y));
                float xo = x[(size_t)m * D + n];
                out[(size_t)m * D + n] = g * fmaxf(y, 0.f) + (1.f - g) * xo;
            }
        }
    }
}

// ---------------- kernel 3: additive self-attention (whole b-tile in LDS) ----------------
// block per (branch, b, i-half); 256 threads; grid = 256 (1 block/CU)
#define XS 451   // padded row stride (451 % 32 = 3 -> conflict-free-ish)

__global__ __launch_bounds__(256) void attn2_kernel(
    const float* __restrict__ x,
    const int* __restrict__ q1_len, const int* __restrict__ q2_len,
    const float* __restrict__ attn_w, const float* __restrict__ attn_b,
    int layer, int add_resid, float* __restrict__ out)
{
    const int bid    = blockIdx.x;          // 0..255
    const int branch = bid >> 7;
    const int b      = (bid >> 1) & 63;
    const int half   = bid & 1;
    const int tid    = threadIdx.x;

    __shared__ float X[L * XS];             // 115.5 KB
    __shared__ float ws3[D];
    __shared__ float s1s[L], s2s[L];
    __shared__ float a_s[32 * L];           // 8 KB

    const float* xb = x + (size_t)(branch * B + b) * L * D;
    // stage x tile
    for (int r = 0; r < L; ++r)
        for (int d = tid; d < D; d += 256)
            X[r * XS + d] = xb[(size_t)r * D + d];
    const float* w3p = attn_w + (size_t)layer * 3 * D + 2 * D;
    for (int d = tid; d < D; d += 256) ws3[d] = w3p[d];
    __syncthreads();

    // s1[i] = x_i . w1 ; s2[j] = x_j . w2   (independent of the pair!)
    if (tid < 128) {
        const int r = tid & 63;
        const float* wv = attn_w + (size_t)layer * 3 * D + (tid >> 6) * D;
        float s = 0.f;
        for (int d = 0; d < D; ++d) s = fmaf(X[r * XS + d], wv[d], s);
        if (tid < 64) s1s[r] = s; else s2s[r] = s;
    }
    __syncthreads();

    // scores: thread (iq, j) computes dot(x_i o w3, x_j) for 8 i's
    const int j  = tid & 63;
    const int iq = tid >> 6;
    const int ibase = half * 32 + iq * 8;
    float acc[8] = {};
#pragma unroll 2
    for (int d = 0; d < D; ++d) {
        float t = X[j * XS + d] * ws3[d];
#pragma unroll
        for (int ii = 0; ii < 8; ++ii)
            acc[ii] = fmaf(X[(ibase + ii) * XS + d], t, acc[ii]);
    }

    const int   len  = (branch ? q2_len : q1_len)[b];
    const float bias = attn_b[layer];
#pragma unroll
    for (int ii = 0; ii < 8; ++ii) {
        const int i = ibase + ii;
        float s = acc[ii] + s1s[i] + s2s[j] + bias;
        if (j >= len) s = -1e-9f;           // reference's (buggy) mask value
        const float mx = wave_max(s);
        const float ev = __expf(s - mx);
        const float sm = wave_sum(ev);
        a_s[(iq * 8 + ii) * L + j] = ev / sm;
    }
    __syncthreads();

    // AV (+ fused residual): out[i] = sum_j a[i][j] x_j (+ x_i)
    float* obase = out + (size_t)(branch * B + b) * L * D;
#pragma unroll 1
    for (int li = 0; li < 32; ++li) {
        const int i = half * 32 + li;
        float* orow = obase + (size_t)i * D;
        for (int d = tid; d < D; d += 256) {
            float a = 0.f;
#pragma unroll 8
            for (int jj = 0; jj < L; ++jj)
                a = fmaf(a_s[li * L + jj], X[jj * XS + d], a);
            if (add_resid) a += X[i * XS + d];
            orow[d] = a;
        }
    }
}

// ---------------- launch ----------------
extern "C" void kernel_launch(void* const* d_in, const int* in_sizes, int n_in,
                              void* d_out, int out_size, void* d_ws, size_t ws_size,
                              hipStream_t stream) {
    const int*   q1       = (const int*)  d_in[0];
    const int*   q2       = (const int*)  d_in[1];
    const int*   q1_len   = (const int*)  d_in[2];
    const int*   q2_len   = (const int*)  d_in[3];
    const int*   q1c      = (const int*)  d_in[4];
    const int*   q2c      = (const int*)  d_in[5];
    const float* word_emb = (const float*)d_in[6];
    const float* char_emb = (const float*)d_in[7];
    const float* w3       = (const float*)d_in[8];
    const float* b3       = (const float*)d_in[9];
    const float* w4       = (const float*)d_in[10];
    const float* b4       = (const float*)d_in[11];
    const float* w5       = (const float*)d_in[12];
    const float* b5       = (const float*)d_in[13];
    const float* hw_w     = (const float*)d_in[14];
    const float* hw_b     = (const float*)d_in[15];
    const float* attn_w   = (const float*)d_in[16];
    const float* attn_b   = (const float*)d_in[17];
    float* out = (float*)d_out;

    float* buf0 = (float*)d_ws;
    float* buf1 = buf0 + (size_t)2 * NT * D;

    // 1. embeddings + char conv -> buf0
    wordcopy_kernel<<<2 * NT / 4, 256, 0, stream>>>(q1, q2, word_emb, buf0);
    conv_kernel<3, 0>  <<<256, 256, 0, stream>>>(q1c, q2c, char_emb, w3, b3, buf0);
    conv_kernel<4, 50> <<<256, 256, 0, stream>>>(q1c, q2c, char_emb, w4, b4, buf0);
    conv_kernel<5, 100><<<256, 256, 0, stream>>>(q1c, q2c, char_emb, w5, b5, buf0);

    // 2. highway x2 (ping-pong)
    dim3 hgrid((D + BN - 1) / BN, (2 * NT) / BM);
    highway_kernel<<<hgrid, 256, 0, stream>>>(buf0, hw_w, hw_b, buf1);
    highway_kernel<<<hgrid, 256, 0, stream>>>(buf1, hw_w, hw_b, buf0);

    // 3. attn layer 0: writes x1 = x0 + att0 directly (residual fused) -> buf1
    attn2_kernel<<<256, 256, 0, stream>>>(buf0, q1_len, q2_len, attn_w, attn_b, 0, 1, buf1);
    // 4. attn layer 1: att only -> d_out
    attn2_kernel<<<256, 256, 0, stream>>>(buf1, q1_len, q2_len, attn_w, attn_b, 1, 0, out);
}